// Round 5
// baseline (658.997 us; speedup 1.0000x reference)
//
#include <hip/hip_runtime.h>
#include <hip/hip_bf16.h>

#define DEV static __device__ __forceinline__

typedef __attribute__((ext_vector_type(4))) float f32x4;
typedef __attribute__((ext_vector_type(8))) short bf16x8;

DEV ushort f2bf(float f){
  union { float f; unsigned u; } v; v.f = f;
  return (ushort)((v.u + 0x7FFFu + ((v.u >> 16) & 1u)) >> 16);
}
DEV float bf2f(ushort u){
  union { unsigned u; float f; } v; v.u = ((unsigned)u) << 16;
  return v.f;
}

// async global->LDS, 16B per lane; LDS dest is wave-uniform base + lane*16.
DEV void gload16(const ushort* g, ushort* l) {
  __builtin_amdgcn_global_load_lds(
      (const __attribute__((address_space(1))) unsigned*)g,
      (__attribute__((address_space(3))) unsigned*)l, 16, 0, 0);
}

// ---------------------------------------------------------------------------
// Elementwise f32 -> bf16 (8 elems/thread, grid-stride).
// ---------------------------------------------------------------------------
__global__ __launch_bounds__(256)
void cvt_bf16(const float* __restrict__ src, ushort* __restrict__ dst, long n8)
{
  const long stride = (long)gridDim.x * 256;
  for (long i = (long)blockIdx.x * 256 + threadIdx.x; i < n8; i += stride) {
    const float4 a = *(const float4*)(src + i * 8);
    const float4 b = *(const float4*)(src + i * 8 + 4);
    union { ushort u[8]; uint4 v; } pk;
    pk.u[0] = f2bf(a.x); pk.u[1] = f2bf(a.y); pk.u[2] = f2bf(a.z); pk.u[3] = f2bf(a.w);
    pk.u[4] = f2bf(b.x); pk.u[5] = f2bf(b.y); pk.u[6] = f2bf(b.z); pk.u[7] = f2bf(b.w);
    *(uint4*)(dst + i * 8) = pk.v;
  }
}

// ---------------------------------------------------------------------------
// bf16 GEMM, relaxed-group schedule: C[M,N] = (A[M,K] @ B^T)*scale, B [N,K]
// K-contiguous. 256x256 tile, 8 waves (2x4, each 128x64 of C). K in groups
// of 32; LDS = 4-slot ring (128 KiB) filled by global_load_lds. Exactly ONE
// s_barrier + one counted s_waitcnt vmcnt(4) per group (T4: never drains).
// Ring depth 4 means the DMA target slot (g+2) is never a slot being read
// (g), so no per-phase barriers are needed; the compiler is left free to
// interleave ds_read / MFMA / DMA-issue with partial lgkmcnt waits (visible
// deps), and wave drift overlaps LDS and MFMA pipes across waves (m114).
// Hand-unrolled x4 so the ring index is compile-time (no VALU on LDS addrs).
// [kb][row][8] subtiling: linear for the DMA, conflict-free ds_read_b128.
// Requires M%256==0, N%256==0, K%128==0 (NG=K/32 multiple of 4, >=4).
// ---------------------------------------------------------------------------
template<bool BY_FAST>
__global__ __launch_bounds__(512, 2)
void gemm_grp(const ushort* __restrict__ A, const ushort* __restrict__ B,
              ushort* __restrict__ C, int K, int N, int nbx, int nby,
              long sA, long sB, long sC, float scale)
{
  __shared__ __align__(16) ushort Ag[4][4][256][8];  // 64 KB ring x kb x row x 8
  __shared__ __align__(16) ushort Bg[4][4][256][8];  // 64 KB

  const int tid = threadIdx.x, lane = tid & 63, wid = tid >> 6;
  const int wr = wid >> 2, wc = wid & 3;  // 2 x 4 waves, each 128x64 of C

  // bijective XCD-chunk swizzle (m204)
  const int nwg = gridDim.x;
  const int q = nwg >> 3, r = nwg & 7;
  const int xcd = blockIdx.x & 7, lid = blockIdx.x >> 3;
  const int id = (xcd < r ? xcd * (q + 1) : r * (q + 1) + (xcd - r) * q) + lid;
  const int per = nbx * nby;
  const int z = id / per, rem = id - z * per;
  const int bx = BY_FAST ? rem / nby : rem % nbx;
  const int by = BY_FAST ? rem % nby : rem / nbx;

  const int bm = by * 256, bn = bx * 256;
  const long Ab = (long)z * sA, Bb = (long)z * sB, Cb = (long)z * sC;

  f32x4 acc[8][4];
  #pragma unroll
  for (int i = 0; i < 8; i++)
    #pragma unroll
    for (int j = 0; j < 4; j++)
      acc[i][j] = (f32x4){0.f, 0.f, 0.f, 0.f};

  // Staging: 16 A-chunks + 16 B-chunks of 1KB per group; wave w owns chunks
  // {2w, 2w+1} of each: kb = c>>2, rb = c&3. 4 gload16 per wave per group.
  const int c0 = wid * 2, c1 = wid * 2 + 1;
  const int kb0 = c0 >> 2, rb0 = c0 & 3, kb1 = c1 >> 2, rb1 = c1 & 3;
  const ushort* ag0 = A + Ab + (long)(bm + rb0 * 64 + lane) * K + kb0 * 8;
  const ushort* ag1 = A + Ab + (long)(bm + rb1 * 64 + lane) * K + kb1 * 8;
  const ushort* bg0 = B + Bb + (long)(bn + rb0 * 64 + lane) * K + kb0 * 8;
  const ushort* bg1 = B + Bb + (long)(bn + rb1 * 64 + lane) * K + kb1 * 8;

  auto STAGE = [&](int g, int rg) {
    gload16(ag0 + g * 32, &Ag[rg][kb0][rb0 * 64][0]);
    gload16(ag1 + g * 32, &Ag[rg][kb1][rb1 * 64][0]);
    gload16(bg0 + g * 32, &Bg[rg][kb0][rb0 * 64][0]);
    gload16(bg1 + g * 32, &Bg[rg][kb1][rb1 * 64][0]);
  };

  const int NG = K >> 5;  // multiple of 4 (K%128==0)
  STAGE(0, 0);
  STAGE(1, 1);
  asm volatile("s_waitcnt vmcnt(4)" ::: "memory");  // group 0 landed; g1 in flight
  __builtin_amdgcn_s_barrier();

  const int lkb = lane >> 4, lrow = lane & 15;

  // One group: stage g+2, read 12 frags, 32 MFMA, counted vmcnt, barrier.
  auto GROUP = [&](int g, int rg, int rg2) {
    if (g + 2 < NG) STAGE(g + 2, rg2);
    bf16x8 av[8], bv[4];
    #pragma unroll
    for (int mi = 0; mi < 8; mi++)
      av[mi] = *(const bf16x8*)&Ag[rg][lkb][wr * 128 + mi * 16 + lrow][0];
    #pragma unroll
    for (int ni = 0; ni < 4; ni++)
      bv[ni] = *(const bf16x8*)&Bg[rg][lkb][wc * 64 + ni * 16 + lrow][0];
    __builtin_amdgcn_s_setprio(1);
    #pragma unroll
    for (int mi = 0; mi < 8; mi++)
      #pragma unroll
      for (int ni = 0; ni < 4; ni++)
        acc[mi][ni] = __builtin_amdgcn_mfma_f32_16x16x32_bf16(av[mi], bv[ni], acc[mi][ni], 0, 0, 0);
    __builtin_amdgcn_s_setprio(0);
    // group boundary: g+1's 4 loads must have landed for all waves; keep
    // g+2's 4 in flight (counted, never drains mid-loop).
    if (g + 2 < NG)      asm volatile("s_waitcnt vmcnt(4)" ::: "memory");
    else if (g + 1 < NG) asm volatile("s_waitcnt vmcnt(0)" ::: "memory");
    __builtin_amdgcn_s_barrier();
  };

  for (int g = 0; g < NG; g += 4) {
    GROUP(g + 0, 0, 2);
    GROUP(g + 1, 1, 3);
    GROUP(g + 2, 2, 0);
    GROUP(g + 3, 3, 1);
  }

  // C/D layout: col=lane&15, row=(lane>>4)*4+reg (m89-verified).
  #pragma unroll
  for (int mi = 0; mi < 8; mi++)
    #pragma unroll
    for (int ni = 0; ni < 4; ni++)
      #pragma unroll
      for (int r2 = 0; r2 < 4; r2++) {
        const int row = bm + wr * 128 + mi * 16 + (lane >> 4) * 4 + r2;
        const int col = bn + wc * 64 + ni * 16 + (lane & 15);
        C[Cb + (long)row * N + col] = f2bf(acc[mi][ni][r2] * scale);
      }
}

// ---------------------------------------------------------------------------
// Softmax over c (2048) per (b,s) row of S (bf16); wsum[b,c] += softmax row.
// Wave owns 32 rows in regs; cross-wave LDS reduce; one atomicAdd/c/block.
// ---------------------------------------------------------------------------
__global__ __launch_bounds__(256)
void softmax_wsum(const ushort* __restrict__ S, float* __restrict__ wsum)
{
  const int b = blockIdx.x;
  const int s0 = blockIdx.y * 128;
  const int lane = threadIdx.x & 63;
  const int w = threadIdx.x >> 6;
  __shared__ float red[4][2048];
  const ushort* Sb = S + (((long)b * 1024) + s0 + w * 32) * 2048;

  float acc[32];
  #pragma unroll
  for (int i = 0; i < 32; i++) acc[i] = 0.f;

  for (int r = 0; r < 32; r++) {
    const ushort* row = Sb + (long)r * 2048;
    float v[32];
    #pragma unroll
    for (int i = 0; i < 4; i++) {
      uint4 u = *(const uint4*)(row + i * 512 + lane * 8);
      const ushort* up = (const ushort*)&u;
      #pragma unroll
      for (int j = 0; j < 8; j++) v[i * 8 + j] = bf2f(up[j]);
    }
    float m = v[0];
    #pragma unroll
    for (int i = 1; i < 32; i++) m = fmaxf(m, v[i]);
    #pragma unroll
    for (int o = 1; o < 64; o <<= 1) m = fmaxf(m, __shfl_xor(m, o));
    float ssum = 0.f;
    #pragma unroll
    for (int i = 0; i < 32; i++) { v[i] = __expf(v[i] - m); ssum += v[i]; }
    #pragma unroll
    for (int o = 1; o < 64; o <<= 1) ssum += __shfl_xor(ssum, o);
    const float inv = 1.f / ssum;
    #pragma unroll
    for (int i = 0; i < 32; i++) acc[i] += v[i] * inv;
  }

  #pragma unroll
  for (int i = 0; i < 4; i++)
    #pragma unroll
    for (int j = 0; j < 8; j++)
      red[w][i * 512 + lane * 8 + j] = acc[i * 8 + j];
  __syncthreads();

  float* wb = wsum + b * 2048;
  #pragma unroll
  for (int k = 0; k < 8; k++) {
    const int c = k * 256 + threadIdx.x;
    atomicAdd(&wb[c], red[0][c] + red[1][c] + red[2][c] + red[3][c]);
  }
}

// t[b,d] = sum_c wsum[b,c] * cyc16[b,c,d].  320 threads, 4 d's each (uint4
// row segments, fully coalesced); 64-c chunks; 4 atomicAdds per thread.
__global__ __launch_bounds__(320)
void wcyc_kernel(const ushort* __restrict__ cyc, const float* __restrict__ wsum,
                 float* __restrict__ t)
{
  const int b = blockIdx.x;
  const int c0 = blockIdx.y * 64;
  const int d = threadIdx.x * 4;
  const ushort* cb = cyc + ((long)b * 2048 + c0) * 1280 + d;
  const float* wb = wsum + b * 2048 + c0;
  float4 a = {0.f, 0.f, 0.f, 0.f};
  for (int c = 0; c < 64; c++) {
    const ushort4 u = *(const ushort4*)(cb + (long)c * 1280);
    const float w = wb[c];
    a.x += w * bf2f(u.x); a.y += w * bf2f(u.y);
    a.z += w * bf2f(u.z); a.w += w * bf2f(u.w);
  }
  atomicAdd(&t[b * 1280 + d + 0], a.x);
  atomicAdd(&t[b * 1280 + d + 1], a.y);
  atomicAdd(&t[b * 1280 + d + 2], a.z);
  atomicAdd(&t[b * 1280 + d + 3], a.w);
}

// xcat[b, 1280+d] = mean_s sub16[b,s,d]
__global__ __launch_bounds__(256)
void submean_kernel(const ushort* __restrict__ sub, float* __restrict__ xcat)
{
  const int b = blockIdx.x;
  const int d = blockIdx.y * 256 + threadIdx.x;
  const int s0 = blockIdx.z * 256;
  const ushort* sb = sub + ((long)b * 1024 + s0) * 1280 + d;
  float a = 0.f;
  for (int s = 0; s < 256; s++) a += bf2f(sb[(long)s * 1280]);
  atomicAdd(&xcat[b * 2560 + 1280 + d], a * (1.f / 1024.f));
}

// xcat[b, dp] = (1/1024) * sum_d t[b,d] * Wv[d,dp]
__global__ __launch_bounds__(256)
void xv_kernel(const float* __restrict__ t, const float* __restrict__ Wv,
               float* __restrict__ xcat)
{
  const int b = blockIdx.y;
  const int dp = blockIdx.x * 256 + threadIdx.x;
  __shared__ float tl[1280];
  for (int i = threadIdx.x; i < 1280; i += 256) tl[i] = t[b * 1280 + i];
  __syncthreads();
  float a = 0.f;
  for (int d = 0; d < 1280; d++) a += tl[d] * Wv[(long)d * 1280 + dp];
  xcat[b * 2560 + dp] = a * (1.f / 1024.f);
}

// h1 = relu(xcat @ W1 + b1)
__global__ __launch_bounds__(256)
void mlp1_kernel(const float* __restrict__ xcat, const float* __restrict__ W1,
                 const float* __restrict__ b1, float* __restrict__ h1)
{
  const int b = blockIdx.y;
  const int j = blockIdx.x * 256 + threadIdx.x;
  __shared__ float xl[2560];
  for (int i = threadIdx.x; i < 2560; i += 256) xl[i] = xcat[b * 2560 + i];
  __syncthreads();
  float a = b1[j];
  for (int d = 0; d < 2560; d++) a += xl[d] * W1[(long)d * 512 + j];
  h1[b * 512 + j] = fmaxf(a, 0.f);
}

// h2 = relu(h1 @ W2 + b2); out = sigmoid(h2 @ W3 + b3)
__global__ __launch_bounds__(64)
void mlp23_kernel(const float* __restrict__ h1, const float* __restrict__ W2,
                  const float* __restrict__ b2, const float* __restrict__ W3,
                  const float* __restrict__ b3, float* __restrict__ out)
{
  const int b = blockIdx.x;
  const int j = threadIdx.x;  // 64 threads = 1 wave
  __shared__ float hl[512];
  for (int i = j; i < 512; i += 64) hl[i] = h1[b * 512 + i];
  __syncthreads();
  float a = b2[j];
  for (int d = 0; d < 512; d++) a += hl[d] * W2[d * 64 + j];
  a = fmaxf(a, 0.f);
  float p = a * W3[j];
  #pragma unroll
  for (int o = 1; o < 64; o <<= 1) p += __shfl_xor(p, o);
  if (j == 0) out[b] = 1.f / (1.f + __expf(-(p + b3[0])));
}

extern "C" void kernel_launch(void* const* d_in, const int* in_sizes, int n_in,
                              void* d_out, int out_size, void* d_ws, size_t ws_size,
                              hipStream_t stream)
{
  const float* cyclase   = (const float*)d_in[0];
  const float* substrate = (const float*)d_in[1];
  // d_in[2], d_in[3]: masks — reference's masking is a no-op (replicated bug).
  const float* Wq = (const float*)d_in[4];
  const float* Wk = (const float*)d_in[5];
  const float* Wv = (const float*)d_in[6];
  const float* W1 = (const float*)d_in[7];
  const float* b1 = (const float*)d_in[8];
  const float* W2 = (const float*)d_in[9];
  const float* b2 = (const float*)d_in[10];
  const float* W3 = (const float*)d_in[11];
  const float* b3 = (const float*)d_in[12];
  float* out = (float*)d_out;
  (void)in_sizes; (void)n_in; (void)out_size; (void)ws_size;

  // Workspace (lifetime-aliased, ~193.5 MB):
  //   [0, 84M)            cyc16                     (cvt .. wcyc)
  //   [84M, 151.2M)       sub16(42M)+Mkq(3.3M)   -> S(67.1M) after both dead
  //   [151.2M, 193.1M)    Wq16+Wk16(6.6M)        -> T1(42M) after Mkq-gemm
  //   [193.1M, ...)       wsum/tbuf/xcat/h1
  char* ws = (char*)d_ws;
  ushort* cyc16 = (ushort*)ws;
  char*   base2 = ws + 83886080;
  ushort* sub16 = (ushort*)base2;
  ushort* Mkq   = (ushort*)(base2 + 41943040);
  ushort* S     = (ushort*)base2;
  char*   base3 = base2 + 67108864;
  ushort* T1    = (ushort*)base3;
  ushort* Wq16  = (ushort*)base3;
  ushort* Wk16  = (ushort*)(base3 + 3276800);
  char*   base4 = base3 + 41943040;
  float* wsum = (float*)base4;
  float* tbuf = (float*)(base4 + 131072);
  float* xcat = (float*)(base4 + 131072 + 81920);
  float* h1   = (float*)(base4 + 131072 + 81920 + 163840);

  hipMemsetAsync(wsum, 0, 16 * 2048 * 4, stream);
  hipMemsetAsync(tbuf, 0, 16 * 1280 * 4, stream);
  hipMemsetAsync(xcat, 0, 16 * 2560 * 4, stream);

  cvt_bf16<<<200, 256, 0, stream>>>(Wq, Wq16, 1280l * 1280 / 8);
  cvt_bf16<<<200, 256, 0, stream>>>(Wk, Wk16, 1280l * 1280 / 8);
  cvt_bf16<<<2048, 256, 0, stream>>>(substrate, sub16, 16l * 1024 * 1280 / 8);
  cvt_bf16<<<2048, 256, 0, stream>>>(cyclase, cyc16, 16l * 2048 * 1280 / 8);

  // Mkq = Wk @ Wq^T * (1/sqrt(1280))  [1280,1280]
  gemm_grp<false><<<25, 512, 0, stream>>>(Wk16, Wq16, Mkq,
      1280, 1280, 5, 5, 0, 0, 0, 0.02795084971874737f);

  submean_kernel<<<dim3(16, 5, 4), 256, 0, stream>>>(sub16, xcat);

  // T1 = sub16 @ Mkq^T  [16384,1280]  (bx-fast: A-panel hot, Mkq L2-resident)
  gemm_grp<false><<<320, 512, 0, stream>>>(sub16, Mkq, T1,
      1280, 1280, 5, 64, 0, 0, 0, 1.0f);

  // S[b] = T1[b] @ cyc16[b]^T  [16,1024,2048]  (by-fast: T1[b] L2-resident)
  gemm_grp<true><<<512, 512, 0, stream>>>(T1, cyc16, S,
      1280, 2048, 8, 4, 1024l * 1280, 2048l * 1280, 1024l * 2048, 1.0f);

  softmax_wsum<<<dim3(16, 8), 256, 0, stream>>>(S, wsum);
  wcyc_kernel<<<dim3(16, 32), 320, 0, stream>>>(cyc16, wsum, tbuf);
  xv_kernel<<<dim3(5, 16), 256, 0, stream>>>(tbuf, Wv, xcat);
  mlp1_kernel<<<dim3(2, 16), 256, 0, stream>>>(xcat, W1, b1, h1);
  mlp23_kernel<<<16, 64, 0, stream>>>(h1, W2, b2, W3, b3, out);
}

// Round 6
// 586.468 us; speedup vs baseline: 1.1237x; 1.1237x over previous
//
#include <hip/hip_runtime.h>
#include <hip/hip_bf16.h>

#define DEV static __device__ __forceinline__

typedef __attribute__((ext_vector_type(4)))  float f32x4;
typedef __attribute__((ext_vector_type(16))) float f32x16;
typedef __attribute__((ext_vector_type(8)))  short bf16x8;

DEV ushort f2bf(float f){
  union { float f; unsigned u; } v; v.f = f;
  return (ushort)((v.u + 0x7FFFu + ((v.u >> 16) & 1u)) >> 16);
}
DEV float bf2f(ushort u){
  union { unsigned u; float f; } v; v.u = ((unsigned)u) << 16;
  return v.f;
}

// async global->LDS, 16B per lane; LDS dest is wave-uniform base + lane*16.
DEV void gload16(const ushort* g, ushort* l) {
  __builtin_amdgcn_global_load_lds(
      (const __attribute__((address_space(1))) unsigned*)g,
      (__attribute__((address_space(3))) unsigned*)l, 16, 0, 0);
}

// ---------------------------------------------------------------------------
// Elementwise f32 -> bf16 (8 elems/thread, grid-stride).
// ---------------------------------------------------------------------------
__global__ __launch_bounds__(256)
void cvt_bf16(const float* __restrict__ src, ushort* __restrict__ dst, long n8)
{
  const long stride = (long)gridDim.x * 256;
  for (long i = (long)blockIdx.x * 256 + threadIdx.x; i < n8; i += stride) {
    const float4 a = *(const float4*)(src + i * 8);
    const float4 b = *(const float4*)(src + i * 8 + 4);
    union { ushort u[8]; uint4 v; } pk;
    pk.u[0] = f2bf(a.x); pk.u[1] = f2bf(a.y); pk.u[2] = f2bf(a.z); pk.u[3] = f2bf(a.w);
    pk.u[4] = f2bf(b.x); pk.u[5] = f2bf(b.y); pk.u[6] = f2bf(b.z); pk.u[7] = f2bf(b.w);
    *(uint4*)(dst + i * 8) = pk.v;
  }
}

// ---------------------------------------------------------------------------
// bf16 GEMM, 8-phase (m201-style), MFMA 32x32x16: C = (A @ B^T)*scale,
// B is [N,K] K-contiguous. BM=BN tile (256 or 128), 8 waves (2x4), wave tile
// (BM/2)x(BM/4). K in groups of 32; LDS = 4-slot ring filled by
// global_load_lds. Per phase: {ds_read frags, issue DMA, s_barrier,
// setprio(1), MFMA cluster, setprio(0), barrier}; compiler inserts partial
// lgkmcnt waits for the visible LDS reads (no manual pins). Group boundary:
// counted s_waitcnt vmcnt(N) — next group's loads stay in flight (T3+T4).
// Frag layout 32x32x16: row=lane&31, k-half=lane>>5 -> b128 from
// [kb][row][8] subtiling (linear for DMA, conflict-free).
// C/D: col=lane&31, row=(reg&3)+8*(reg>>2)+4*(lane>>5)  (m74/m101).
// Requires M%BM==0, N%BM==0, K%128==0.
// ---------------------------------------------------------------------------
template<int BM, bool BY_FAST>
__global__ __launch_bounds__(512, (BM == 256 ? 2 : 4))
void gemm8p(const ushort* __restrict__ A, const ushort* __restrict__ B,
            ushort* __restrict__ C, int K, int N, int nbx, int nby,
            long sA, long sB, long sC, float scale)
{
  constexpr int MT  = BM / 64;   // 32x32 m-tiles per wave (4 or 2)
  constexpr int NT2 = BM / 128;  // 32x32 n-tiles per wave (2 or 1)
  constexpr int NRQ = BM / 64;   // 64-row chunk-blocks per slot (4 or 2)
  __shared__ __align__(16) ushort As[4][4][BM][8];
  __shared__ __align__(16) ushort Bs[4][4][BM][8];

  const int tid = threadIdx.x, lane = tid & 63, wid = tid >> 6;
  const int wr = wid >> 2, wc = wid & 3;  // 2 x 4 waves

  // bijective XCD-chunk swizzle (m204)
  const int nwg = gridDim.x;
  const int q = nwg >> 3, r = nwg & 7;
  const int xcd = blockIdx.x & 7, lid = blockIdx.x >> 3;
  const int id = (xcd < r ? xcd * (q + 1) : r * (q + 1) + (xcd - r) * q) + lid;
  const int per = nbx * nby;
  const int z = id / per, rem = id - z * per;
  const int bx = BY_FAST ? rem / nby : rem % nbx;
  const int by = BY_FAST ? rem % nby : rem / nbx;

  const int bm = by * BM, bn = bx * BM;
  const long Ab = (long)z * sA, Bb = (long)z * sB, Cb = (long)z * sC;

  f32x16 acc[MT][NT2];
  #pragma unroll
  for (int i = 0; i < MT; i++)
    #pragma unroll
    for (int j = 0; j < NT2; j++)
      #pragma unroll
      for (int e = 0; e < 16; e++)
        acc[i][j][e] = 0.f;

  // Staging: BM/16 A-chunks + BM/16 B-chunks of 1KB/group over 8 waves.
  // BM=256: wave stages A{2w,2w+1} in phase alpha, B{2w,2w+1} in beta.
  // BM=128: wave stages A{w} and B{w} in the single phase.
  constexpr int APW = BM / 128;          // A-loads per wave per group (2 or 1)
  constexpr int VMN = 4 * APW / 2 * 2;   // boundary outstanding = 2*APW*2/2... (4 or 2)
  const int cA = wid * APW;
  const int kbA0 = cA / NRQ, rqA0 = cA % NRQ;
  const int kbA1 = (cA + 1) / NRQ, rqA1 = (cA + 1) % NRQ;

  const ushort* agp0 = A + Ab + (long)(bm + rqA0 * 64 + lane) * K + kbA0 * 8;
  const ushort* agp1 = A + Ab + (long)(bm + rqA1 * 64 + lane) * K + kbA1 * 8;
  const ushort* bgp0 = B + Bb + (long)(bn + rqA0 * 64 + lane) * K + kbA0 * 8;
  const ushort* bgp1 = B + Bb + (long)(bn + rqA1 * 64 + lane) * K + kbA1 * 8;

  auto STAGE_A = [&](int g, int rg) {
    gload16(agp0 + g * 32, &As[rg][kbA0][rqA0 * 64][0]);
    if constexpr (APW == 2) gload16(agp1 + g * 32, &As[rg][kbA1][rqA1 * 64][0]);
  };
  auto STAGE_B = [&](int g, int rg) {
    gload16(bgp0 + g * 32, &Bs[rg][kbA0][rqA0 * 64][0]);
    if constexpr (APW == 2) gload16(bgp1 + g * 32, &Bs[rg][kbA1][rqA1 * 64][0]);
  };

  const int NG = K >> 5;  // multiple of 4
  STAGE_A(0, 0); STAGE_B(0, 0);
  STAGE_A(1, 1); STAGE_B(1, 1);
  if constexpr (BM == 256) asm volatile("s_waitcnt vmcnt(4)" ::: "memory");
  else                     asm volatile("s_waitcnt vmcnt(2)" ::: "memory");
  __builtin_amdgcn_s_barrier();

  const int lrow = lane & 31, lkh = lane >> 5;

  auto GROUP = [&](int g, int rg, int rg2) {
    const bool pre = (g + 2 < NG);
    bf16x8 bv[NT2][2];
    #pragma unroll
    for (int ni = 0; ni < NT2; ni++)
      #pragma unroll
      for (int kf = 0; kf < 2; kf++)
        bv[ni][kf] = *(const bf16x8*)&Bs[rg][kf * 2 + lkh][wc * (BM / 4) + ni * 32 + lrow][0];
    if constexpr (BM == 256) {
      // ---- phase alpha: m-tiles 0,1 ----
      bf16x8 av[2][2];
      #pragma unroll
      for (int mi = 0; mi < 2; mi++)
        #pragma unroll
        for (int kf = 0; kf < 2; kf++)
          av[mi][kf] = *(const bf16x8*)&As[rg][kf * 2 + lkh][wr * (BM / 2) + mi * 32 + lrow][0];
      if (pre) STAGE_A(g + 2, rg2);
      __builtin_amdgcn_s_barrier();
      __builtin_amdgcn_s_setprio(1);
      #pragma unroll
      for (int mi = 0; mi < 2; mi++)
        #pragma unroll
        for (int ni = 0; ni < NT2; ni++)
          #pragma unroll
          for (int kf = 0; kf < 2; kf++)
            acc[mi][ni] = __builtin_amdgcn_mfma_f32_32x32x16_bf16(av[mi][kf], bv[ni][kf], acc[mi][ni], 0, 0, 0);
      __builtin_amdgcn_s_setprio(0);
      __builtin_amdgcn_s_barrier();
      // ---- phase beta: m-tiles 2,3 (bv reused) ----
      #pragma unroll
      for (int mi = 0; mi < 2; mi++)
        #pragma unroll
        for (int kf = 0; kf < 2; kf++)
          av[mi][kf] = *(const bf16x8*)&As[rg][kf * 2 + lkh][wr * (BM / 2) + (mi + 2) * 32 + lrow][0];
      if (pre) STAGE_B(g + 2, rg2);
      __builtin_amdgcn_s_barrier();
      __builtin_amdgcn_s_setprio(1);
      #pragma unroll
      for (int mi = 0; mi < 2; mi++)
        #pragma unroll
        for (int ni = 0; ni < NT2; ni++)
          #pragma unroll
          for (int kf = 0; kf < 2; kf++)
            acc[mi + 2][ni] = __builtin_amdgcn_mfma_f32_32x32x16_bf16(av[mi][kf], bv[ni][kf], acc[mi + 2][ni], 0, 0, 0);
      __builtin_amdgcn_s_setprio(0);
      if (pre)                asm volatile("s_waitcnt vmcnt(4)" ::: "memory");
      else if (g + 1 < NG)    asm volatile("s_waitcnt vmcnt(0)" ::: "memory");
      __builtin_amdgcn_s_barrier();
    } else {
      // ---- single phase: m-tiles 0,1, n-tile 0 ----
      bf16x8 av[2][2];
      #pragma unroll
      for (int mi = 0; mi < 2; mi++)
        #pragma unroll
        for (int kf = 0; kf < 2; kf++)
          av[mi][kf] = *(const bf16x8*)&As[rg][kf * 2 + lkh][wr * (BM / 2) + mi * 32 + lrow][0];
      if (pre) { STAGE_A(g + 2, rg2); STAGE_B(g + 2, rg2); }
      __builtin_amdgcn_s_barrier();
      __builtin_amdgcn_s_setprio(1);
      #pragma unroll
      for (int mi = 0; mi < 2; mi++)
        #pragma unroll
        for (int kf = 0; kf < 2; kf++)
          acc[mi][0] = __builtin_amdgcn_mfma_f32_32x32x16_bf16(av[mi][kf], bv[0][kf], acc[mi][0], 0, 0, 0);
      __builtin_amdgcn_s_setprio(0);
      if (pre)                asm volatile("s_waitcnt vmcnt(2)" ::: "memory");
      else if (g + 1 < NG)    asm volatile("s_waitcnt vmcnt(0)" ::: "memory");
      __builtin_amdgcn_s_barrier();
    }
  };

  for (int g = 0; g < NG; g += 4) {
    GROUP(g + 0, 0, 2);
    GROUP(g + 1, 1, 3);
    GROUP(g + 2, 2, 0);
    GROUP(g + 3, 3, 1);
  }

  // C/D 32x32: col=lane&31, row=(reg&3)+8*(reg>>2)+4*(lane>>5).
  #pragma unroll
  for (int mi = 0; mi < MT; mi++)
    #pragma unroll
    for (int ni = 0; ni < NT2; ni++)
      #pragma unroll
      for (int rg2 = 0; rg2 < 16; rg2++) {
        const int row = bm + wr * (BM / 2) + mi * 32 + (rg2 & 3) + 8 * (rg2 >> 2) + 4 * lkh;
        const int col = bn + wc * (BM / 4) + ni * 32 + lrow;
        C[Cb + (long)row * N + col] = f2bf(acc[mi][ni][rg2] * scale);
      }
}

// ---------------------------------------------------------------------------
// Softmax over c (2048) per (b,s) row of S (bf16); wsum[b,c] += softmax row.
// 512 blocks (16 x 32): wave owns 8 rows in regs; cross-wave LDS reduce;
// one atomicAdd per c per block.
// ---------------------------------------------------------------------------
__global__ __launch_bounds__(256)
void softmax_wsum(const ushort* __restrict__ S, float* __restrict__ wsum)
{
  const int b = blockIdx.x;
  const int s0 = blockIdx.y * 32;
  const int lane = threadIdx.x & 63;
  const int w = threadIdx.x >> 6;
  __shared__ float red[4][2048];
  const ushort* Sb = S + (((long)b * 1024) + s0 + w * 8) * 2048;

  float acc[32];
  #pragma unroll
  for (int i = 0; i < 32; i++) acc[i] = 0.f;

  for (int r = 0; r < 8; r++) {
    const ushort* row = Sb + (long)r * 2048;
    float v[32];
    #pragma unroll
    for (int i = 0; i < 4; i++) {
      uint4 u = *(const uint4*)(row + i * 512 + lane * 8);
      const ushort* up = (const ushort*)&u;
      #pragma unroll
      for (int j = 0; j < 8; j++) v[i * 8 + j] = bf2f(up[j]);
    }
    float m = v[0];
    #pragma unroll
    for (int i = 1; i < 32; i++) m = fmaxf(m, v[i]);
    #pragma unroll
    for (int o = 1; o < 64; o <<= 1) m = fmaxf(m, __shfl_xor(m, o));
    float ssum = 0.f;
    #pragma unroll
    for (int i = 0; i < 32; i++) { v[i] = __expf(v[i] - m); ssum += v[i]; }
    #pragma unroll
    for (int o = 1; o < 64; o <<= 1) ssum += __shfl_xor(ssum, o);
    const float inv = 1.f / ssum;
    #pragma unroll
    for (int i = 0; i < 32; i++) acc[i] += v[i] * inv;
  }

  #pragma unroll
  for (int i = 0; i < 4; i++)
    #pragma unroll
    for (int j = 0; j < 8; j++)
      red[w][i * 512 + lane * 8 + j] = acc[i * 8 + j];
  __syncthreads();

  float* wb = wsum + b * 2048;
  #pragma unroll
  for (int k = 0; k < 8; k++) {
    const int c = k * 256 + threadIdx.x;
    atomicAdd(&wb[c], red[0][c] + red[1][c] + red[2][c] + red[3][c]);
  }
}

// t[b,d] = sum_c wsum[b,c] * cyc16[b,c,d]. 320 threads, 4 d's each (uint4
// row segments, fully coalesced); 64-c chunks; 4 atomicAdds per thread.
__global__ __launch_bounds__(320)
void wcyc_kernel(const ushort* __restrict__ cyc, const float* __restrict__ wsum,
                 float* __restrict__ t)
{
  const int b = blockIdx.x;
  const int c0 = blockIdx.y * 64;
  const int d = threadIdx.x * 4;
  const ushort* cb = cyc + ((long)b * 2048 + c0) * 1280 + d;
  const float* wb = wsum + b * 2048 + c0;
  float4 a = {0.f, 0.f, 0.f, 0.f};
  for (int c = 0; c < 64; c++) {
    const ushort4 u = *(const ushort4*)(cb + (long)c * 1280);
    const float w = wb[c];
    a.x += w * bf2f(u.x); a.y += w * bf2f(u.y);
    a.z += w * bf2f(u.z); a.w += w * bf2f(u.w);
  }
  atomicAdd(&t[b * 1280 + d + 0], a.x);
  atomicAdd(&t[b * 1280 + d + 1], a.y);
  atomicAdd(&t[b * 1280 + d + 2], a.z);
  atomicAdd(&t[b * 1280 + d + 3], a.w);
}

// xcat[b, 1280+d] = mean_s sub16[b,s,d]
__global__ __launch_bounds__(256)
void submean_kernel(const ushort* __restrict__ sub, float* __restrict__ xcat)
{
  const int b = blockIdx.x;
  const int d = blockIdx.y * 256 + threadIdx.x;
  const int s0 = blockIdx.z * 256;
  const ushort* sb = sub + ((long)b * 1024 + s0) * 1280 + d;
  float a = 0.f;
  for (int s = 0; s < 256; s++) a += bf2f(sb[(long)s * 1280]);
  atomicAdd(&xcat[b * 2560 + 1280 + d], a * (1.f / 1024.f));
}

// xcat[b, dp] = (1/1024) * sum_d t[b,d] * Wv[d,dp]
__global__ __launch_bounds__(256)
void xv_kernel(const float* __restrict__ t, const float* __restrict__ Wv,
               float* __restrict__ xcat)
{
  const int b = blockIdx.y;
  const int dp = blockIdx.x * 256 + threadIdx.x;
  __shared__ float tl[1280];
  for (int i = threadIdx.x; i < 1280; i += 256) tl[i] = t[b * 1280 + i];
  __syncthreads();
  float a = 0.f;
  for (int d = 0; d < 1280; d++) a += tl[d] * Wv[(long)d * 1280 + dp];
  xcat[b * 2560 + dp] = a * (1.f / 1024.f);
}

// h1 = relu(xcat @ W1 + b1)
__global__ __launch_bounds__(256)
void mlp1_kernel(const float* __restrict__ xcat, const float* __restrict__ W1,
                 const float* __restrict__ b1, float* __restrict__ h1)
{
  const int b = blockIdx.y;
  const int j = blockIdx.x * 256 + threadIdx.x;
  __shared__ float xl[2560];
  for (int i = threadIdx.x; i < 2560; i += 256) xl[i] = xcat[b * 2560 + i];
  __syncthreads();
  float a = b1[j];
  for (int d = 0; d < 2560; d++) a += xl[d] * W1[(long)d * 512 + j];
  h1[b * 512 + j] = fmaxf(a, 0.f);
}

// h2 = relu(h1 @ W2 + b2); out = sigmoid(h2 @ W3 + b3)
__global__ __launch_bounds__(64)
void mlp23_kernel(const float* __restrict__ h1, const float* __restrict__ W2,
                  const float* __restrict__ b2, const float* __restrict__ W3,
                  const float* __restrict__ b3, float* __restrict__ out)
{
  const int b = blockIdx.x;
  const int j = threadIdx.x;  // 64 threads = 1 wave
  __shared__ float hl[512];
  for (int i = j; i < 512; i += 64) hl[i] = h1[b * 512 + i];
  __syncthreads();
  float a = b2[j];
  for (int d = 0; d < 512; d++) a += hl[d] * W2[d * 64 + j];
  a = fmaxf(a, 0.f);
  float p = a * W3[j];
  #pragma unroll
  for (int o = 1; o < 64; o <<= 1) p += __shfl_xor(p, o);
  if (j == 0) out[b] = 1.f / (1.f + __expf(-(p + b3[0])));
}

extern "C" void kernel_launch(void* const* d_in, const int* in_sizes, int n_in,
                              void* d_out, int out_size, void* d_ws, size_t ws_size,
                              hipStream_t stream)
{
  const float* cyclase   = (const float*)d_in[0];
  const float* substrate = (const float*)d_in[1];
  // d_in[2], d_in[3]: masks — reference's masking is a no-op (replicated bug).
  const float* Wq = (const float*)d_in[4];
  const float* Wk = (const float*)d_in[5];
  const float* Wv = (const float*)d_in[6];
  const float* W1 = (const float*)d_in[7];
  const float* b1 = (const float*)d_in[8];
  const float* W2 = (const float*)d_in[9];
  const float* b2 = (const float*)d_in[10];
  const float* W3 = (const float*)d_in[11];
  const float* b3 = (const float*)d_in[12];
  float* out = (float*)d_out;
  (void)in_sizes; (void)n_in; (void)out_size; (void)ws_size;

  // Workspace (lifetime-aliased, ~193.5 MB):
  //   [0, 84M)            cyc16                     (cvt .. wcyc)
  //   [84M, 151.2M)       sub16(42M)+Mkq(3.3M)   -> S(67.1M) after both dead
  //   [151.2M, 193.1M)    Wq16+Wk16(6.6M)        -> T1(42M) after Mkq-gemm
  //   [193.1M, ...)       wsum/tbuf/xcat/h1
  char* ws = (char*)d_ws;
  ushort* cyc16 = (ushort*)ws;
  char*   base2 = ws + 83886080;
  ushort* sub16 = (ushort*)base2;
  ushort* Mkq   = (ushort*)(base2 + 41943040);
  ushort* S     = (ushort*)base2;
  char*   base3 = base2 + 67108864;
  ushort* T1    = (ushort*)base3;
  ushort* Wq16  = (ushort*)base3;
  ushort* Wk16  = (ushort*)(base3 + 3276800);
  char*   base4 = base3 + 41943040;
  float* wsum = (float*)base4;
  float* tbuf = (float*)(base4 + 131072);
  float* xcat = (float*)(base4 + 131072 + 81920);
  float* h1   = (float*)(base4 + 131072 + 81920 + 163840);

  hipMemsetAsync(wsum, 0, 16 * 2048 * 4, stream);
  hipMemsetAsync(tbuf, 0, 16 * 1280 * 4, stream);
  hipMemsetAsync(xcat, 0, 16 * 2560 * 4, stream);

  cvt_bf16<<<200, 256, 0, stream>>>(Wq, Wq16, 1280l * 1280 / 8);
  cvt_bf16<<<200, 256, 0, stream>>>(Wk, Wk16, 1280l * 1280 / 8);
  cvt_bf16<<<2048, 256, 0, stream>>>(substrate, sub16, 16l * 1024 * 1280 / 8);
  cvt_bf16<<<2048, 256, 0, stream>>>(cyclase, cyc16, 16l * 2048 * 1280 / 8);

  // Mkq = Wk @ Wq^T * (1/sqrt(1280))  [1280,1280]  (BM=128: 100 blocks)
  gemm8p<128, false><<<100, 512, 0, stream>>>(Wk16, Wq16, Mkq,
      1280, 1280, 10, 10, 0, 0, 0, 0.02795084971874737f);

  submean_kernel<<<dim3(16, 5, 4), 256, 0, stream>>>(sub16, xcat);

  // T1 = sub16 @ Mkq^T  [16384,1280]  (BM=128: 1280 blocks = 5 even rounds)
  gemm8p<128, false><<<1280, 512, 0, stream>>>(sub16, Mkq, T1,
      1280, 1280, 10, 128, 0, 0, 0, 1.0f);

  // S[b] = T1[b] @ cyc16[b]^T  [16,1024,2048]  (BM=256, by-fast)
  gemm8p<256, true><<<512, 512, 0, stream>>>(T1, cyc16, S,
      1280, 2048, 8, 4, 1024l * 1280, 2048l * 1280, 1024l * 2048, 1.0f);

  softmax_wsum<<<dim3(16, 32), 256, 0, stream>>>(S, wsum);
  wcyc_kernel<<<dim3(16, 32), 320, 0, stream>>>(cyc16, wsum, tbuf);
  xv_kernel<<<dim3(5, 16), 256, 0, stream>>>(tbuf, Wv, xcat);
  mlp1_kernel<<<dim3(2, 16), 256, 0, stream>>>(xcat, W1, b1, h1);
  mlp23_kernel<<<16, 64, 0, stream>>>(h1, W2, b2, W3, b3, out);
}